// Round 1
// baseline (233.732 us; speedup 1.0000x reference)
//
#include <hip/hip_runtime.h>

// B=16, T=256, C=6, E=512, H=8, hd=64.
// Inputs fp32 (reference dtype); OUTPUT fp32 (reference dtype).
// Compute in bf16 MFMA; biases added in fp32.
//
// Round 5 change: replace the m97-style 128x128 GEMM (serial stage->drain->MFMA,
// ~30% of MFMA ceiling) with a 256x128-tile, BK=64, 8-wave kernel using the
// 8-phase-template levers: triple-buffered LDS + counted vmcnt(6) (never
// drains to 0 in the main loop), 2 phases per K-tile with raw s_barrier,
// setprio(1) around each 16-MFMA cluster, and the T2 XOR swizzle
// (byte ^= (row&7)<<4) applied on the pre-swizzled global source (gl_lds dest
// stays linear) and on the ds_read side.

typedef unsigned short u16;
typedef short bf16x8 __attribute__((ext_vector_type(8)));   // 8 bf16 = 4 VGPRs
typedef float f32x4 __attribute__((ext_vector_type(4)));
typedef u16 u16x4 __attribute__((ext_vector_type(4)));

#define MFMA16(a, b, c) __builtin_amdgcn_mfma_f32_16x16x32_bf16((a), (b), (c), 0, 0, 0)

__device__ __forceinline__ u16 f2b(float f) {
  union { float f; unsigned u; } v; v.f = f;
  unsigned r = v.u + 0x7fffu + ((v.u >> 16) & 1u);   // RNE (finite inputs)
  return (u16)(r >> 16);
}
__device__ __forceinline__ void gl_lds16(const void* g, void* l) {
  __builtin_amdgcn_global_load_lds(
      (const __attribute__((address_space(1))) void*)g,
      (__attribute__((address_space(3))) void*)l, 16, 0, 0);
}

// ---------------------------------------------------------------------------
// fp32 -> bf16 converters
// ---------------------------------------------------------------------------
__global__ void cvt_w(const float* W0, const float* W1, const float* W2,
                      const float* W3, u16* dst) {
  const float* src = (blockIdx.y == 0) ? W0 : (blockIdx.y == 1) ? W1
                   : (blockIdx.y == 2) ? W2 : W3;
  const int idx = (blockIdx.x * 256 + threadIdx.x) * 4;
  f32x4 v = *(const f32x4*)(src + idx);
  u16x4 o; o.x = f2b(v.x); o.y = f2b(v.y); o.z = f2b(v.z); o.w = f2b(v.w);
  *(u16x4*)(dst + (size_t)blockIdx.y * 262144 + idx) = o;
}

__global__ void cvt_x(const float* __restrict__ src, u16* __restrict__ dst) {
  const size_t idx = ((size_t)blockIdx.x * 256 + threadIdx.x) * 4;
  f32x4 v = *(const f32x4*)(src + idx);
  u16x4 o; o.x = f2b(v.x); o.y = f2b(v.y); o.z = f2b(v.z); o.w = f2b(v.w);
  *(u16x4*)(dst + idx) = o;
}

// ---------------------------------------------------------------------------
// 256x128-tile BT-GEMM, BK=64, 512 threads = 8 waves (4M x 2N), wave out 64x64.
// C[m][n] = sum_k A[m][k]*W[n][k] + b[n].  K = 512 fixed (8 K-tiles).
// LDS: 3 buffers x (A 256x64 + B 128x64) bf16 = 144 KB, 1 block/CU.
// Main loop: compute tile kt from buf[kt%3]; issue tile kt+2 into buf[(kt+2)%3]
// (3 gl_lds per phase); iteration-end wait is counted vmcnt(6) (tile kt+1's 6
// loads are one full iteration old -> free), vmcnt(0) only at kt==6.
// qkv_mode=1: z selects W/bias, bf16 scatter-store to [b,h,c,t,d].
// qkv_mode=0: fp32 row-major store to OF.
// ---------------------------------------------------------------------------
__global__ __launch_bounds__(512, 2) void gemm256(
    const u16* __restrict__ A,
    const u16* W0, const u16* W1, const u16* W2,
    const float* bs0, const float* bs1, const float* bs2,
    u16* O0, u16* O1, u16* O2,
    float* OF,
    int qkv_mode)
{
  const int z = blockIdx.z;
  const u16* W    = (z == 0) ? W0 : (z == 1) ? W1 : W2;
  const float* bs = (z == 0) ? bs0 : (z == 1) ? bs1 : bs2;
  u16* O          = (z == 0) ? O0 : (z == 1) ? O1 : O2;

  const int m0 = blockIdx.x * 256;
  const int n0 = blockIdx.y * 128;

  __shared__ u16 As[3][256 * 64];   // 3 x 32 KB, 128 B rows
  __shared__ u16 Bs[3][128 * 64];   // 3 x 16 KB, 128 B rows

  const int tid  = threadIdx.x;
  const int lane = tid & 63;
  const int wv   = tid >> 6;
  const int r    = lane & 15;
  const int qd   = lane >> 4;
  const int wr   = wv >> 1;         // 0..3 : wave m-row
  const int wc   = wv & 1;          // 0..1 : wave n-col

  // Staging: per K-tile, A = 4 gl_lds/thread, B = 2 gl_lds/thread (16 B each).
  // LDS dest is linear (flat); source column is XOR-swizzled so that
  // LDS[row][c16] holds global[row][c16 ^ (row&7)] (16B units).
  const char* srcA[4]; const char* srcB[2];
  int flatA[4], flatB[2];
  #pragma unroll
  for (int j = 0; j < 4; ++j) {
    const int flat = (j * 512 + tid) * 16;
    const int row  = flat >> 7;                 // 128 B per row
    const int c16  = (flat >> 4) & 7;
    flatA[j] = flat;
    srcA[j]  = (const char*)A + (size_t)(m0 + row) * 1024 + ((c16 ^ (row & 7)) << 4);
  }
  #pragma unroll
  for (int j = 0; j < 2; ++j) {
    const int flat = (j * 512 + tid) * 16;
    const int row  = flat >> 7;
    const int c16  = (flat >> 4) & 7;
    flatB[j] = flat;
    srcB[j]  = (const char*)W + (size_t)(n0 + row) * 1024 + ((c16 ^ (row & 7)) << 4);
  }

  // ds_read addressing: frag row uses +r; row&7 == r&7 (16-row frag stride),
  // so the swizzle term is wave-constant per lane.
  const int sw   = (r & 7) << 4;
  const int colq = qd * 16;
  int arow[4], brow[4];
  #pragma unroll
  for (int mt = 0; mt < 4; ++mt) arow[mt] = (wr * 64 + mt * 16 + r) * 128;
  #pragma unroll
  for (int nt = 0; nt < 4; ++nt) brow[nt] = (wc * 64 + nt * 16 + r) * 128;

  f32x4 acc[4][4] = {};

  // Prologue: stage tiles 0 and 1 (12 gl_lds), wait for tile 0 only.
  #pragma unroll
  for (int tt = 0; tt < 2; ++tt) {
    #pragma unroll
    for (int j = 0; j < 4; ++j)
      gl_lds16(srcA[j] + tt * 128, (char*)As[tt] + flatA[j]);
    #pragma unroll
    for (int j = 0; j < 2; ++j)
      gl_lds16(srcB[j] + tt * 128, (char*)Bs[tt] + flatB[j]);
  }
  asm volatile("s_waitcnt vmcnt(6)\n\ts_barrier" ::: "memory");

  #pragma unroll
  for (int kt = 0; kt < 8; ++kt) {
    const int cb  = kt % 3;            // compute buffer (compile-time: unrolled)
    const int pb  = (kt + 2) % 3;      // prefetch buffer
    const bool pre = (kt + 2) < 8;

    #pragma unroll
    for (int kc = 0; kc < 2; ++kc) {
      const int co = (kc * 64 + colq);
      bf16x8 af[4], bf[4];
      #pragma unroll
      for (int mt = 0; mt < 4; ++mt)
        af[mt] = *(const bf16x8*)((const char*)As[cb] + arow[mt] + (co ^ sw));
      #pragma unroll
      for (int nt = 0; nt < 4; ++nt)
        bf[nt] = *(const bf16x8*)((const char*)Bs[cb] + brow[nt] + (co ^ sw));

      if (pre) {                        // 3 staging issues per phase
        if (kc == 0) {
          gl_lds16(srcA[0] + (kt + 2) * 128, (char*)As[pb] + flatA[0]);
          gl_lds16(srcA[1] + (kt + 2) * 128, (char*)As[pb] + flatA[1]);
          gl_lds16(srcB[0] + (kt + 2) * 128, (char*)Bs[pb] + flatB[0]);
        } else {
          gl_lds16(srcA[2] + (kt + 2) * 128, (char*)As[pb] + flatA[2]);
          gl_lds16(srcA[3] + (kt + 2) * 128, (char*)As[pb] + flatA[3]);
          gl_lds16(srcB[1] + (kt + 2) * 128, (char*)Bs[pb] + flatB[1]);
        }
      }

      asm volatile("s_barrier" ::: "memory");
      __builtin_amdgcn_s_setprio(1);
      #pragma unroll
      for (int mt = 0; mt < 4; ++mt)
        #pragma unroll
        for (int nt = 0; nt < 4; ++nt)
          acc[mt][nt] = MFMA16(af[mt], bf[nt], acc[mt][nt]);
      __builtin_amdgcn_s_setprio(0);

      if (kc == 0) {
        asm volatile("s_barrier" ::: "memory");
      } else if (kt < 6) {
        // tile kt+1 (issued last iteration) must be landed; tile kt+2's 6
        // loads (issued this iteration) may stay in flight.
        asm volatile("s_waitcnt vmcnt(6)\n\ts_barrier" ::: "memory");
      } else if (kt == 6) {
        asm volatile("s_waitcnt vmcnt(0)\n\ts_barrier" ::: "memory");
      }
      // kt==7, kc==1: fall through to epilogue (LDS no longer needed)
    }
  }

  float bv[4];
  #pragma unroll
  for (int nt = 0; nt < 4; ++nt) bv[nt] = bs[n0 + wc * 64 + nt * 16 + r];

  if (qkv_mode) {
    #pragma unroll
    for (int mt = 0; mt < 4; ++mt) {
      #pragma unroll
      for (int rr = 0; rr < 4; ++rr) {
        const int m   = m0 + wr * 64 + mt * 16 + qd * 4 + rr;  // (b*T+t)*C + c
        const int b   = m / 1536;
        const int rem = m - b * 1536;
        const int t   = rem / 6;
        const int c   = rem - t * 6;
        #pragma unroll
        for (int nt = 0; nt < 4; ++nt) {
          const int f = n0 + wc * 64 + nt * 16 + r;            // h*64 + d
          const int h = f >> 6;
          const int d = f & 63;
          const size_t addr = ((((size_t)b * 8 + h) * 6 + c) * 256 + t) * 64 + d;
          O[addr] = f2b(acc[mt][nt][rr] + bv[nt]);
        }
      }
    }
  } else {
    #pragma unroll
    for (int mt = 0; mt < 4; ++mt) {
      #pragma unroll
      for (int rr = 0; rr < 4; ++rr) {
        const int m = m0 + wr * 64 + mt * 16 + qd * 4 + rr;
        #pragma unroll
        for (int nt = 0; nt < 4; ++nt) {
          const int f = n0 + wc * 64 + nt * 16 + r;
          OF[(size_t)m * 512 + f] = acc[mt][nt][rr] + bv[nt];   // fp32 output
        }
      }
    }
  }
}

// ---------------------------------------------------------------------------
// Causal attention, one block per (b,h,c).  512 threads = 8 waves.
// Wave w owns query tiles {w, 15-w}; keys in 2 super-chunks of 128.
// LDS = 18+17+18 = 53 KB.
// ---------------------------------------------------------------------------
__global__ __launch_bounds__(512, 2) void attn(
    const u16* __restrict__ q_ws, const u16* __restrict__ k_ws,
    const u16* __restrict__ v_ws, u16* __restrict__ y_ws)
{
  const int blk = blockIdx.x;            // (b*8 + h)*6 + c  (b slab-local)
  const int b   = blk / 48;
  const int h   = (blk / 6) % 8;
  const int c   = blk % 6;
  const size_t base = (size_t)blk * 256 * 64;

  __shared__ u16 Ks[128 * 72];           // 18 KB  K super-chunk, padded stride
  __shared__ u16 Vts[64 * 136];          // 17 KB  V^T super-chunk
  __shared__ u16 Ps[8][16 * 72];         // 18 KB  per-wave P tile

  const int tid  = threadIdx.x;
  const int lane = tid & 63;
  const int wv   = tid >> 6;
  const int r    = lane & 15;
  const int qd   = lane >> 4;

  const int tiles[2] = { wv, 15 - wv };

  bf16x8 qf[2][2];
  #pragma unroll
  for (int ti = 0; ti < 2; ++ti)
    #pragma unroll
    for (int kc = 0; kc < 2; ++kc)
      qf[ti][kc] = *(const bf16x8*)(q_ws + base +
                     (size_t)(tiles[ti] * 16 + r) * 64 + kc * 32 + qd * 8);

  f32x4 o_acc[2][4] = {};
  float l_acc[2][4] = {{0.f,0.f,0.f,0.f},{0.f,0.f,0.f,0.f}};

  for (int sc = 0; sc < 2; ++sc) {
    __syncthreads();
    #pragma unroll
    for (int it = 0; it < 2; ++it) {
      const int idx = it * 512 + tid;
      const int row = idx >> 3;
      const int c8  = idx & 7;
      *(bf16x8*)(Ks + row * 72 + c8 * 8) =
          *(const bf16x8*)(k_ws + base + (size_t)(sc * 128 + row) * 64 + c8 * 8);
    }
    {
      const int jl = tid & 127;
      const int d0 = (tid >> 7) * 16;
      #pragma unroll
      for (int dd = 0; dd < 16; dd += 8) {
        bf16x8 vv = *(const bf16x8*)(v_ws + base +
                       (size_t)(sc * 128 + jl) * 64 + d0 + dd);
        #pragma unroll
        for (int e = 0; e < 8; ++e)
          Vts[(d0 + dd + e) * 136 + jl] = ((u16*)&vv)[e];
      }
    }
    __syncthreads();

    #pragma unroll
    for (int ti = 0; ti < 2; ++ti) {
      const int mt  = tiles[ti];
      const int i0  = mt * 16;
      const int nch = (mt >> 2) + 1;
      #pragma unroll
      for (int jcl = 0; jcl < 2; ++jcl) {
        const int jc = sc * 2 + jcl;
        if (jc >= nch) continue;            // wave-uniform skip
        const int j0l = jcl * 64;
        const int j0g = sc * 128 + j0l;

        f32x4 s[4] = {};
        #pragma unroll
        for (int nt = 0; nt < 4; ++nt)
          #pragma unroll
          for (int kc = 0; kc < 2; ++kc) {
            bf16x8 kf = *(const bf16x8*)(Ks + (j0l + nt * 16 + r) * 72 +
                                         kc * 32 + qd * 8);
            s[nt] = MFMA16(qf[ti][kc], kf, s[nt]);
          }

        #pragma unroll
        for (int nt = 0; nt < 4; ++nt)
          #pragma unroll
          for (int rr = 0; rr < 4; ++rr) {
            const int i = i0 + qd * 4 + rr;
            const int j = j0g + nt * 16 + r;
            float p = __builtin_exp2f(fminf(s[nt][rr], 500.f) *
                                      0.1803368801111244f);  // *(1/8)*log2(e)
            if (j > i) p = 0.f;
            l_acc[ti][rr] += p;
            Ps[wv][(qd * 4 + rr) * 72 + nt * 16 + r] = f2b(p);
          }
        asm volatile("s_waitcnt lgkmcnt(0)" ::: "memory");

        bf16x8 pf[2];
        #pragma unroll
        for (int kc = 0; kc < 2; ++kc)
          pf[kc] = *(const bf16x8*)(Ps[wv] + r * 72 + kc * 32 + qd * 8);
        #pragma unroll
        for (int ntd = 0; ntd < 4; ++ntd)
          #pragma unroll
          for (int kc = 0; kc < 2; ++kc) {
            bf16x8 vf = *(const bf16x8*)(Vts + (ntd * 16 + r) * 136 +
                                         j0l + kc * 32 + qd * 8);
            o_acc[ti][ntd] = MFMA16(pf[kc], vf, o_acc[ti][ntd]);
          }
      }
    }
  }

  const size_t obase = ((size_t)b * 256) * 3072 + h * 384 + c * 64;
  #pragma unroll
  for (int ti = 0; ti < 2; ++ti) {
    const int i0 = tiles[ti] * 16;
    float linv[4];
    #pragma unroll
    for (int rr = 0; rr < 4; ++rr) {
      float sum = l_acc[ti][rr];
      sum += __shfl_xor(sum, 1, 16);
      sum += __shfl_xor(sum, 2, 16);
      sum += __shfl_xor(sum, 4, 16);
      sum += __shfl_xor(sum, 8, 16);
      linv[rr] = 1.f / sum;
    }
    #pragma unroll
    for (int ntd = 0; ntd < 4; ++ntd)
      #pragma unroll
      for (int rr = 0; rr < 4; ++rr) {
        const int t = i0 + qd * 4 + rr;
        const int d = ntd * 16 + r;
        y_ws[obase + (size_t)t * 3072 + d] = f2b(o_acc[ti][ntd][rr] * linv[rr]);
      }
  }
}

// ---------------------------------------------------------------------------
extern "C" void kernel_launch(void* const* d_in, const int* in_sizes, int n_in,
                              void* d_out, int out_size, void* d_ws, size_t ws_size,
                              hipStream_t stream) {
  const float* x  = (const float*)d_in[0];
  const float* Wq = (const float*)d_in[1];
  const float* bq = (const float*)d_in[2];
  const float* Wk = (const float*)d_in[3];
  const float* bk = (const float*)d_in[4];
  const float* Wv = (const float*)d_in[5];
  const float* bv = (const float*)d_in[6];
  const float* Wp = (const float*)d_in[7];
  const float* bp = (const float*)d_in[8];
  float* out = (float*)d_out;                        // fp32 output

  const size_t PER_B = 256 * 6 * 512;       // 786432 elems per tensor per batch
  const size_t WSEG  = 4 * 262144;          // converted weights: Wq,Wk,Wv,Wp

  int NB = 16;
  while (NB > 1 && (WSEG + (size_t)5 * NB * PER_B) * 2 > ws_size) NB >>= 1;

  u16* wbf = (u16*)d_ws;
  u16* Wqb = wbf;
  u16* Wkb = wbf + 262144;
  u16* Wvb = wbf + 2 * 262144;
  u16* Wpb = wbf + 3 * 262144;

  const size_t slab = (size_t)NB * PER_B;
  u16* xbf  = wbf + WSEG;
  u16* q_ws = xbf + slab;
  u16* k_ws = q_ws + slab;
  u16* v_ws = k_ws + slab;
  u16* y_ws = v_ws + slab;

  cvt_w<<<dim3(256, 4), 256, 0, stream>>>(Wq, Wk, Wv, Wp, wbf);

  const int nslab = 16 / NB;
  for (int s = 0; s < nslab; ++s) {
    const float* x_s  = x   + (size_t)s * NB * PER_B;
    float*      out_s = out + (size_t)s * NB * PER_B;
    cvt_x<<<dim3(NB * 768), 256, 0, stream>>>(x_s, xbf);
    gemm256<<<dim3(NB * 6, 4, 3), 512, 0, stream>>>(
        xbf, Wqb, Wkb, Wvb, bq, bk, bv, q_ws, k_ws, v_ws, nullptr, 1);
    attn<<<dim3(NB * 48), 512, 0, stream>>>(q_ws, k_ws, v_ws, y_ws);
    gemm256<<<dim3(NB * 6, 4, 1), 512, 0, stream>>>(
        y_ws, Wpb, Wpb, Wpb, bp, bp, bp, nullptr, nullptr, nullptr, out_s, 0);
  }
}

// Round 2
// 225.098 us; speedup vs baseline: 1.0384x; 1.0384x over previous
//
#include <hip/hip_runtime.h>

// B=16, T=256, C=6, E=512, H=8, hd=64.
// Inputs fp32 (reference dtype); OUTPUT fp32 (reference dtype).
// Compute in bf16 MFMA; biases added in fp32.
//
// Round 6: revert to the proven 128x128 / 256-thread gemm (r4: 61 µs) and fix
// its one structural stall WITHOUT losing residency:
//  - triple-buffered LDS (3 x 16 KB = 48 KB -> still 3 blocks/CU, matching the
//    VGPR+AGPR limit), prefetch tile kt+2 while computing kt, end-of-step wait
//    is a free counted vmcnt(4) (tile kt+1's loads are one full K-step old).
//    vmcnt(0) only once (kt==14). One barrier per K-step instead of two.
//  - QKV z-dim fused into the n-dimension (grid x = 12 n-blocks, n-fast order)
//    so the 12 blocks sharing an A-panel are dispatch-adjacent -> A read from
//    HBM once; single dispatch instead of z=3.

typedef unsigned short u16;
typedef short bf16x8 __attribute__((ext_vector_type(8)));   // 8 bf16 = 4 VGPRs
typedef float f32x4 __attribute__((ext_vector_type(4)));
typedef u16 u16x4 __attribute__((ext_vector_type(4)));

#define MFMA16(a, b, c) __builtin_amdgcn_mfma_f32_16x16x32_bf16((a), (b), (c), 0, 0, 0)

__device__ __forceinline__ u16 f2b(float f) {
  union { float f; unsigned u; } v; v.f = f;
  unsigned r = v.u + 0x7fffu + ((v.u >> 16) & 1u);   // RNE (finite inputs)
  return (u16)(r >> 16);
}
__device__ __forceinline__ void gl_lds16(const void* g, void* l) {
  __builtin_amdgcn_global_load_lds(
      (const __attribute__((address_space(1))) void*)g,
      (__attribute__((address_space(3))) void*)l, 16, 0, 0);
}

// ---------------------------------------------------------------------------
// fp32 -> bf16 converters
// ---------------------------------------------------------------------------
__global__ void cvt_w(const float* W0, const float* W1, const float* W2,
                      const float* W3, u16* dst) {
  const float* src = (blockIdx.y == 0) ? W0 : (blockIdx.y == 1) ? W1
                   : (blockIdx.y == 2) ? W2 : W3;
  const int idx = (blockIdx.x * 256 + threadIdx.x) * 4;
  f32x4 v = *(const f32x4*)(src + idx);
  u16x4 o; o.x = f2b(v.x); o.y = f2b(v.y); o.z = f2b(v.z); o.w = f2b(v.w);
  *(u16x4*)(dst + (size_t)blockIdx.y * 262144 + idx) = o;
}

__global__ void cvt_x(const float* __restrict__ src, u16* __restrict__ dst) {
  const size_t idx = ((size_t)blockIdx.x * 256 + threadIdx.x) * 4;
  f32x4 v = *(const f32x4*)(src + idx);
  u16x4 o; o.x = f2b(v.x); o.y = f2b(v.y); o.z = f2b(v.z); o.w = f2b(v.w);
  *(u16x4*)(dst + idx) = o;
}

// ---------------------------------------------------------------------------
// BT-GEMM, 128x128 tile, 256 threads = 4 waves (2x2), wave out 64x64.
// C[m][n] = sum_k A[m][k]*W[n][k] + b[n].  K = 512 fixed (16 K-steps of 32).
// grid: x = n-block (n-fast; qkv: 12 -> sel = x>>2 picks W/bias/O),
//       y = m-block.
// LDS: 3 buffers x (A 128x32 + B 128x32) = 48 KB -> 3 blocks/CU (= reg limit).
// Pipeline: compute kt from buf[kt%3]; prefetch kt+2 into buf[(kt+2)%3];
// end-of-step wait = vmcnt(4) (counted), vmcnt(0) only at kt==14.
// qkv_mode=1: bf16 scatter-store to [b,h,c,t,d].  qkv_mode=0: fp32 row-major.
// ---------------------------------------------------------------------------
__global__ __launch_bounds__(256, 3) void gemm_bt(
    const u16* __restrict__ A,
    const u16* W0, const u16* W1, const u16* W2,
    const float* bs0, const float* bs1, const float* bs2,
    u16* O0, u16* O1, u16* O2,
    float* OF,
    int qkv_mode)
{
  const int bx  = blockIdx.x;
  const int sel = bx >> 2;                 // 0..2 (qkv) / 0 (proj)
  const u16* W    = (sel == 0) ? W0 : (sel == 1) ? W1 : W2;
  const float* bs = (sel == 0) ? bs0 : (sel == 1) ? bs1 : bs2;
  u16* O          = (sel == 0) ? O0 : (sel == 1) ? O1 : O2;

  const int m0 = blockIdx.y * 128;
  const int nl = (bx & 3) * 128;           // column within the selected matrix

  __shared__ u16 As[3][128 * 32];   // 3 x 8 KB, 64B rows, chunk swizzle
  __shared__ u16 Bs[3][128 * 32];   //   (q + (row>>1)) & 3

  const int tid  = threadIdx.x;
  const int lane = tid & 63;
  const int wv   = tid >> 6;
  const int r    = lane & 15;
  const int qd   = lane >> 4;
  const int wm   = (wv & 1) * 64;
  const int wn   = (wv >> 1) * 64;

  // Per-thread staging addresses (K-step-independent parts).
  const char* gA[2]; const char* gB[2]; int fl[2];
  #pragma unroll
  for (int it = 0; it < 2; ++it) {
    const int flat = (it * 256 + tid) * 16;       // byte offset in 8KB tile
    const int row  = flat >> 6;                   // 64 B per row
    const int gc   = (((flat >> 4) & 3) - (row >> 1)) & 3;  // un-swizzle
    fl[it] = flat;
    gA[it] = (const char*)A + (size_t)(m0 + row) * 1024 + gc * 16;
    gB[it] = (const char*)W + (size_t)(nl + row) * 1024 + gc * 16;
  }

  f32x4 acc[4][4] = {};

  // Prologue: stage K-tiles 0 and 1, wait for tile 0 only.
  #pragma unroll
  for (int tt = 0; tt < 2; ++tt)
    #pragma unroll
    for (int it = 0; it < 2; ++it) {
      gl_lds16(gA[it] + tt * 64, (char*)As[tt] + fl[it]);
      gl_lds16(gB[it] + tt * 64, (char*)Bs[tt] + fl[it]);
    }
  asm volatile("s_waitcnt vmcnt(4)\n\ts_barrier" ::: "memory");

  #pragma unroll
  for (int kt = 0; kt < 16; ++kt) {
    const int cb = kt % 3;                 // compile-time after unroll
    const int pb = (kt + 2) % 3;

    if (kt + 2 < 16) {                     // prefetch tile kt+2 (4 gl_lds)
      #pragma unroll
      for (int it = 0; it < 2; ++it) {
        gl_lds16(gA[it] + (kt + 2) * 64, (char*)As[pb] + fl[it]);
        gl_lds16(gB[it] + (kt + 2) * 64, (char*)Bs[pb] + fl[it]);
      }
    }

    bf16x8 af[4], bf[4];
    #pragma unroll
    for (int mt = 0; mt < 4; ++mt) {
      const int row = wm + mt * 16 + r;
      const int sw  = (qd + (row >> 1)) & 3;
      af[mt] = *(const bf16x8*)((const char*)As[cb] + row * 64 + sw * 16);
    }
    #pragma unroll
    for (int nt = 0; nt < 4; ++nt) {
      const int row = wn + nt * 16 + r;
      const int sw  = (qd + (row >> 1)) & 3;
      bf[nt] = *(const bf16x8*)((const char*)Bs[cb] + row * 64 + sw * 16);
    }
    #pragma unroll
    for (int mt = 0; mt < 4; ++mt)
      #pragma unroll
      for (int nt = 0; nt < 4; ++nt)
        acc[mt][nt] = MFMA16(af[mt], bf[nt], acc[mt][nt]);

    // Buffer (kt+2)%3 is overwritten in iteration kt+1 -> this barrier
    // (placed after all reads of buf[cb]=buf[(kt+3)%3... ] of THIS iter)
    // protects it.  Counted wait: tile kt+1's 4 loads are one full K-step
    // old; tile kt+2's 4 may stay in flight.
    if (kt < 14) {
      asm volatile("s_waitcnt vmcnt(4)\n\ts_barrier" ::: "memory");
    } else if (kt == 14) {
      asm volatile("s_waitcnt vmcnt(0)\n\ts_barrier" ::: "memory");
    }
    // kt==15: fall through to epilogue (LDS no longer needed)
  }

  float bv[4];
  #pragma unroll
  for (int nt = 0; nt < 4; ++nt) bv[nt] = bs[nl + wn + nt * 16 + r];

  if (qkv_mode) {
    #pragma unroll
    for (int mt = 0; mt < 4; ++mt) {
      #pragma unroll
      for (int rr = 0; rr < 4; ++rr) {
        const int m   = m0 + wm + mt * 16 + qd * 4 + rr;   // (b*T+t)*C + c
        const int b   = m / 1536;
        const int rem = m - b * 1536;
        const int t   = rem / 6;
        const int c   = rem - t * 6;
        #pragma unroll
        for (int nt = 0; nt < 4; ++nt) {
          const int f = nl + wn + nt * 16 + r;             // h*64 + d
          const int h = f >> 6;
          const int d = f & 63;
          const size_t addr = ((((size_t)b * 8 + h) * 6 + c) * 256 + t) * 64 + d;
          O[addr] = f2b(acc[mt][nt][rr] + bv[nt]);
        }
      }
    }
  } else {
    #pragma unroll
    for (int mt = 0; mt < 4; ++mt) {
      #pragma unroll
      for (int rr = 0; rr < 4; ++rr) {
        const int m = m0 + wm + mt * 16 + qd * 4 + rr;
        #pragma unroll
        for (int nt = 0; nt < 4; ++nt) {
          const int f = nl + wn + nt * 16 + r;
          OF[(size_t)m * 512 + f] = acc[mt][nt][rr] + bv[nt];   // fp32 output
        }
      }
    }
  }
}

// ---------------------------------------------------------------------------
// Causal attention, one block per (b,h,c).  512 threads = 8 waves.
// Wave w owns query tiles {w, 15-w}; keys in 2 super-chunks of 128.
// LDS = 18+17+18 = 53 KB.
// ---------------------------------------------------------------------------
__global__ __launch_bounds__(512, 2) void attn(
    const u16* __restrict__ q_ws, const u16* __restrict__ k_ws,
    const u16* __restrict__ v_ws, u16* __restrict__ y_ws)
{
  const int blk = blockIdx.x;            // (b*8 + h)*6 + c  (b slab-local)
  const int b   = blk / 48;
  const int h   = (blk / 6) % 8;
  const int c   = blk % 6;
  const size_t base = (size_t)blk * 256 * 64;

  __shared__ u16 Ks[128 * 72];           // 18 KB  K super-chunk, padded stride
  __shared__ u16 Vts[64 * 136];          // 17 KB  V^T super-chunk
  __shared__ u16 Ps[8][16 * 72];         // 18 KB  per-wave P tile

  const int tid  = threadIdx.x;
  const int lane = tid & 63;
  const int wv   = tid >> 6;
  const int r    = lane & 15;
  const int qd   = lane >> 4;

  const int tiles[2] = { wv, 15 - wv };

  bf16x8 qf[2][2];
  #pragma unroll
  for (int ti = 0; ti < 2; ++ti)
    #pragma unroll
    for (int kc = 0; kc < 2; ++kc)
      qf[ti][kc] = *(const bf16x8*)(q_ws + base +
                     (size_t)(tiles[ti] * 16 + r) * 64 + kc * 32 + qd * 8);

  f32x4 o_acc[2][4] = {};
  float l_acc[2][4] = {{0.f,0.f,0.f,0.f},{0.f,0.f,0.f,0.f}};

  for (int sc = 0; sc < 2; ++sc) {
    __syncthreads();
    #pragma unroll
    for (int it = 0; it < 2; ++it) {
      const int idx = it * 512 + tid;
      const int row = idx >> 3;
      const int c8  = idx & 7;
      *(bf16x8*)(Ks + row * 72 + c8 * 8) =
          *(const bf16x8*)(k_ws + base + (size_t)(sc * 128 + row) * 64 + c8 * 8);
    }
    {
      const int jl = tid & 127;
      const int d0 = (tid >> 7) * 16;
      #pragma unroll
      for (int dd = 0; dd < 16; dd += 8) {
        bf16x8 vv = *(const bf16x8*)(v_ws + base +
                       (size_t)(sc * 128 + jl) * 64 + d0 + dd);
        #pragma unroll
        for (int e = 0; e < 8; ++e)
          Vts[(d0 + dd + e) * 136 + jl] = ((u16*)&vv)[e];
      }
    }
    __syncthreads();

    #pragma unroll
    for (int ti = 0; ti < 2; ++ti) {
      const int mt  = tiles[ti];
      const int i0  = mt * 16;
      const int nch = (mt >> 2) + 1;
      #pragma unroll
      for (int jcl = 0; jcl < 2; ++jcl) {
        const int jc = sc * 2 + jcl;
        if (jc >= nch) continue;            // wave-uniform skip
        const int j0l = jcl * 64;
        const int j0g = sc * 128 + j0l;

        f32x4 s[4] = {};
        #pragma unroll
        for (int nt = 0; nt < 4; ++nt)
          #pragma unroll
          for (int kc = 0; kc < 2; ++kc) {
            bf16x8 kf = *(const bf16x8*)(Ks + (j0l + nt * 16 + r) * 72 +
                                         kc * 32 + qd * 8);
            s[nt] = MFMA16(qf[ti][kc], kf, s[nt]);
          }

        #pragma unroll
        for (int nt = 0; nt < 4; ++nt)
          #pragma unroll
          for (int rr = 0; rr < 4; ++rr) {
            const int i = i0 + qd * 4 + rr;
            const int j = j0g + nt * 16 + r;
            float p = __builtin_exp2f(fminf(s[nt][rr], 500.f) *
                                      0.1803368801111244f);  // *(1/8)*log2(e)
            if (j > i) p = 0.f;
            l_acc[ti][rr] += p;
            Ps[wv][(qd * 4 + rr) * 72 + nt * 16 + r] = f2b(p);
          }
        asm volatile("s_waitcnt lgkmcnt(0)" ::: "memory");

        bf16x8 pf[2];
        #pragma unroll
        for (int kc = 0; kc < 2; ++kc)
          pf[kc] = *(const bf16x8*)(Ps[wv] + r * 72 + kc * 32 + qd * 8);
        #pragma unroll
        for (int ntd = 0; ntd < 4; ++ntd)
          #pragma unroll
          for (int kc = 0; kc < 2; ++kc) {
            bf16x8 vf = *(const bf16x8*)(Vts + (ntd * 16 + r) * 136 +
                                         j0l + kc * 32 + qd * 8);
            o_acc[ti][ntd] = MFMA16(pf[kc], vf, o_acc[ti][ntd]);
          }
      }
    }
  }

  const size_t obase = ((size_t)b * 256) * 3072 + h * 384 + c * 64;
  #pragma unroll
  for (int ti = 0; ti < 2; ++ti) {
    const int i0 = tiles[ti] * 16;
    float linv[4];
    #pragma unroll
    for (int rr = 0; rr < 4; ++rr) {
      float sum = l_acc[ti][rr];
      sum += __shfl_xor(sum, 1, 16);
      sum += __shfl_xor(sum, 2, 16);
      sum += __shfl_xor(sum, 4, 16);
      sum += __shfl_xor(sum, 8, 16);
      linv[rr] = 1.f / sum;
    }
    #pragma unroll
    for (int ntd = 0; ntd < 4; ++ntd)
      #pragma unroll
      for (int rr = 0; rr < 4; ++rr) {
        const int t = i0 + qd * 4 + rr;
        const int d = ntd * 16 + r;
        y_ws[obase + (size_t)t * 3072 + d] = f2b(o_acc[ti][ntd][rr] * linv[rr]);
      }
  }
}

// ---------------------------------------------------------------------------
extern "C" void kernel_launch(void* const* d_in, const int* in_sizes, int n_in,
                              void* d_out, int out_size, void* d_ws, size_t ws_size,
                              hipStream_t stream) {
  const float* x  = (const float*)d_in[0];
  const float* Wq = (const float*)d_in[1];
  const float* bq = (const float*)d_in[2];
  const float* Wk = (const float*)d_in[3];
  const float* bk = (const float*)d_in[4];
  const float* Wv = (const float*)d_in[5];
  const float* bv = (const float*)d_in[6];
  const float* Wp = (const float*)d_in[7];
  const float* bp = (const float*)d_in[8];
  float* out = (float*)d_out;                        // fp32 output

  const size_t PER_B = 256 * 6 * 512;       // 786432 elems per tensor per batch
  const size_t WSEG  = 4 * 262144;          // converted weights: Wq,Wk,Wv,Wp

  int NB = 16;
  while (NB > 1 && (WSEG + (size_t)5 * NB * PER_B) * 2 > ws_size) NB >>= 1;

  u16* wbf = (u16*)d_ws;
  u16* Wqb = wbf;
  u16* Wkb = wbf + 262144;
  u16* Wvb = wbf + 2 * 262144;
  u16* Wpb = wbf + 3 * 262144;

  const size_t slab = (size_t)NB * PER_B;
  u16* xbf  = wbf + WSEG;
  u16* q_ws = xbf + slab;
  u16* k_ws = q_ws + slab;
  u16* v_ws = k_ws + slab;
  u16* y_ws = v_ws + slab;

  cvt_w<<<dim3(256, 4), 256, 0, stream>>>(Wq, Wk, Wv, Wp, wbf);

  const int nslab = 16 / NB;
  for (int s = 0; s < nslab; ++s) {
    const float* x_s  = x   + (size_t)s * NB * PER_B;
    float*      out_s = out + (size_t)s * NB * PER_B;
    cvt_x<<<dim3(NB * 768), 256, 0, stream>>>(x_s, xbf);
    gemm_bt<<<dim3(12, NB * 12, 1), 256, 0, stream>>>(
        xbf, Wqb, Wkb, Wvb, bq, bk, bv, q_ws, k_ws, v_ws, nullptr, 1);
    attn<<<dim3(NB * 48), 512, 0, stream>>>(q_ws, k_ws, v_ws, y_ws);
    gemm_bt<<<dim3(4, NB * 12, 1), 256, 0, stream>>>(
        y_ws, Wpb, Wpb, Wpb, bp, bp, bp, nullptr, nullptr, nullptr, out_s, 0);
  }
}